// Round 1
// baseline (2074.634 us; speedup 1.0000x reference)
//
#include <hip/hip_runtime.h>
#include <math.h>

#define DT 0.1f
#define EPSL 1e-5f

// ---- output layout (float32, concatenated in reference return order) ----
// Xrec [256,50,1,28,28] = 10035200
// qz0_m [256,8]         = 2048
// qz0_v [256,8]         = 2048
// zt   [256,50,8]       = 102400
// lhood, kl_            = 1 + 1
#define XREC_OFF 0
#define QM_OFF   10035200
#define QV_OFF   10037248
#define ZT_OFF   10039296
#define LH_OFF   10141696
#define KL_OFF   10141697

// ---- workspace layout (bytes) ----
// lhp  float[12800]  @ 0        (51200 B)
// klp  float[256]    @ 51200    (1024 B)
// z0   float[2048]   @ 52224    (8192 B)
// M1   float[784*9]  @ 60416    (28224 B)   fused fc3+convT1: per row m: 8 weights + bias

// =====================================================================
// Prep: M1[m][j] = sum over convT1 taps of dec_w1 * fc3_w (j<8) / fc3_b (j==8, + dec_b1)
// m = oc*49 + oy*7 + ox  (oc<16, 7x7)  — matches y1 LDS layout in decoder
// =====================================================================
__global__ __launch_bounds__(256) void prep_kernel(
    const float* __restrict__ fc3w, const float* __restrict__ fc3b,
    const float* __restrict__ dw1, const float* __restrict__ db1,
    float* __restrict__ M1)
{
    int idx = blockIdx.x * 256 + threadIdx.x;
    if (idx >= 784 * 9) return;
    int m = idx / 9, j = idx % 9;
    int oc = m / 49, r = m % 49, oy = r / 7, ox = r % 7;
    float acc = (j == 8) ? db1[oc] : 0.f;
    for (int ky = 0; ky < 5; ++ky) {
        int ty = oy + ky - 2;
        if (ty < 0 || (ty & 1)) continue;
        int iy = ty >> 1; if (iy >= 4) continue;
        for (int kx = 0; kx < 5; ++kx) {
            int tx = ox + kx - 2;
            if (tx < 0 || (tx & 1)) continue;
            int ix = tx >> 1; if (ix >= 4) continue;
            for (int ic = 0; ic < 32; ++ic) {
                float wv = dw1[((oc * 32 + ic) * 5 + ky) * 5 + kx];
                int mi = ic * 16 + iy * 4 + ix;
                acc += wv * ((j < 8) ? fc3w[mi * 8 + j] : fc3b[mi]);
            }
        }
    }
    M1[m * 9 + j] = acc;
}

// =====================================================================
// Encoder: one block per sample. convs k=5,s=2,p=2. Writes qz0_m, qz0_v,
// z0 (ws), kl per-sample partial (ws).
// =====================================================================
__global__ __launch_bounds__(256) void enc_kernel(
    const float* __restrict__ X, const float* __restrict__ eps,
    const float* __restrict__ w1, const float* __restrict__ b1,
    const float* __restrict__ w2, const float* __restrict__ b2,
    const float* __restrict__ w3, const float* __restrict__ b3,
    const float* __restrict__ fc1w, const float* __restrict__ fc1b,
    const float* __restrict__ fc2w, const float* __restrict__ fc2b,
    float* __restrict__ out, float* __restrict__ z0, float* __restrict__ klp)
{
    __shared__ float img[784];       // 1x28x28
    __shared__ float a1[8 * 196];    // 8x14x14
    __shared__ float a2[16 * 49];    // 16x7x7
    __shared__ float h[512];         // 32x4x4 flattened
    __shared__ float kl_s[8];
    int n = blockIdx.x, tid = threadIdx.x;

    const float* xi = X + (size_t)n * 39200;  // X[n,0,0,:,:]
    for (int i = tid; i < 784; i += 256) img[i] = xi[i];
    __syncthreads();

    // conv1: 1->8, 28->14
    for (int idx = tid; idx < 1568; idx += 256) {
        int oc = idx / 196, r = idx % 196, oy = r / 14, ox = r % 14;
        float acc = b1[oc];
        for (int ky = 0; ky < 5; ++ky) {
            int iy = 2 * oy - 2 + ky; if (iy < 0 || iy >= 28) continue;
            for (int kx = 0; kx < 5; ++kx) {
                int ix = 2 * ox - 2 + kx; if (ix < 0 || ix >= 28) continue;
                acc += w1[oc * 25 + ky * 5 + kx] * img[iy * 28 + ix];
            }
        }
        a1[idx] = fmaxf(acc, 0.f);
    }
    __syncthreads();

    // conv2: 8->16, 14->7
    for (int idx = tid; idx < 784; idx += 256) {
        int oc = idx / 49, r = idx % 49, oy = r / 7, ox = r % 7;
        float acc = b2[oc];
        for (int ic = 0; ic < 8; ++ic)
            for (int ky = 0; ky < 5; ++ky) {
                int iy = 2 * oy - 2 + ky; if (iy < 0 || iy >= 14) continue;
                for (int kx = 0; kx < 5; ++kx) {
                    int ix = 2 * ox - 2 + kx; if (ix < 0 || ix >= 14) continue;
                    acc += w2[((oc * 8 + ic) * 5 + ky) * 5 + kx] * a1[ic * 196 + iy * 14 + ix];
                }
            }
        a2[idx] = fmaxf(acc, 0.f);
    }
    __syncthreads();

    // conv3: 16->32, 7->4
    for (int idx = tid; idx < 512; idx += 256) {
        int oc = idx / 16, r = idx % 16, oy = r / 4, ox = r % 4;
        float acc = b3[oc];
        for (int ic = 0; ic < 16; ++ic)
            for (int ky = 0; ky < 5; ++ky) {
                int iy = 2 * oy - 2 + ky; if (iy < 0 || iy >= 7) continue;
                for (int kx = 0; kx < 5; ++kx) {
                    int ix = 2 * ox - 2 + kx; if (ix < 0 || ix >= 7) continue;
                    acc += w3[((oc * 16 + ic) * 5 + ky) * 5 + kx] * a2[ic * 49 + iy * 7 + ix];
                }
            }
        h[idx] = fmaxf(acc, 0.f);   // layout oc*16 + oy*4 + ox == reshape order
    }
    __syncthreads();

    // fc1/fc2 + reparam + kl (threads 0..7)
    if (tid < 8) {
        float m = fc1b[tid], lv = fc2b[tid];
        for (int k = 0; k < 512; ++k) {
            float hv = h[k];
            m  += fc1w[tid * 512 + k] * hv;
            lv += fc2w[tid * 512 + k] * hv;
        }
        float v = fmaxf(lv, 0.f) + log1pf(expf(-fabsf(lv)));  // softplus
        float z = m + eps[n * 8 + tid] * v;
        out[QM_OFF + n * 8 + tid] = m;
        out[QV_OFF + n * 8 + tid] = v;
        z0[n * 8 + tid] = z;
        kl_s[tid] = -logf(v) + 0.5f * (v * v + m * m) - 0.5f;
    }
    __syncthreads();
    if (tid == 0) {
        float s = 0.f;
        for (int i = 0; i < 8; ++i) s += kl_s[i];
        klp[n] = s;
    }
}

// =====================================================================
// ODE: one block (128 threads) per sample; full 49-step RK4 loop inside.
// Weights in LDS; w1/w2 transposed so lane j reads consecutive addresses.
// =====================================================================
__global__ __launch_bounds__(128) void ode_kernel(
    const float* __restrict__ z0,
    const float* __restrict__ fw1, const float* __restrict__ fb1,
    const float* __restrict__ fw2, const float* __restrict__ fb2,
    const float* __restrict__ fw3, const float* __restrict__ fb3,
    float* __restrict__ ztg)
{
    __shared__ float w1t[800];    // [k<8][j<100]
    __shared__ float b1s[100];
    __shared__ float w2t[10000];  // [k<100][j<100]
    __shared__ float b2s[100];
    __shared__ float w3s[800];    // [i<8][k<100]
    __shared__ float b3s[8];
    __shared__ float v[8], zc[8], kk[3][8], a1[100], h2[100];
    int n = blockIdx.x, tid = threadIdx.x;

    for (int i = tid; i < 800; i += 128) { int j = i >> 3, k = i & 7; w1t[k * 100 + j] = fw1[i]; }
    for (int i = tid; i < 10000; i += 128) { int j = i / 100, k = i % 100; w2t[k * 100 + j] = fw2[i]; }
    for (int i = tid; i < 800; i += 128) w3s[i] = fw3[i];
    for (int i = tid; i < 100; i += 128) { b1s[i] = fb1[i]; b2s[i] = fb2[i]; }
    if (tid < 8) {
        b3s[tid] = fb3[tid];
        float z = z0[n * 8 + tid];
        zc[tid] = z; v[tid] = z;
        ztg[n * 400 + tid] = z;   // zt[n,0,:]
    }
    __syncthreads();

    for (int t = 1; t < 50; ++t) {
        #pragma unroll 1
        for (int st = 0; st < 4; ++st) {
            // layer 1: 8 -> 100
            if (tid < 100) {
                float acc = b1s[tid];
                #pragma unroll
                for (int k = 0; k < 8; ++k) acc += w1t[k * 100 + tid] * v[k];
                a1[tid] = fmaxf(acc, 0.f);
            }
            __syncthreads();
            // layer 2: 100 -> 100
            if (tid < 100) {
                float acc = b2s[tid];
                for (int k = 0; k < 100; ++k) acc += w2t[k * 100 + tid] * a1[k];
                h2[tid] = fmaxf(acc, 0.f);
            }
            __syncthreads();
            // layer 3: 100 -> 8, plus RK4 state update
            if (tid < 8) {
                float acc = b3s[tid];
                for (int k = 0; k < 100; ++k) acc += w3s[tid * 100 + k] * h2[k];
                if (st < 3) {
                    kk[st][tid] = acc;
                    float c = (st == 2) ? DT : 0.5f * DT;
                    v[tid] = zc[tid] + c * acc;
                } else {
                    float zn = zc[tid] + (DT / 6.f) *
                        (kk[0][tid] + 2.f * kk[1][tid] + 2.f * kk[2][tid] + acc);
                    zc[tid] = zn; v[tid] = zn;
                    ztg[n * 400 + t * 8 + tid] = zn;
                }
            }
            __syncthreads();
        }
    }
}

// =====================================================================
// Decoder: one block per (n,t). Fused M1 GEMM -> convT2 -> convT3 ->
// sigmoid -> Xrec + Bernoulli log-likelihood partial.
// =====================================================================
__global__ __launch_bounds__(256) void dec_kernel(
    const float* __restrict__ M1, const float* __restrict__ zt,
    const float* __restrict__ w2, const float* __restrict__ b2,
    const float* __restrict__ w3, const float* __restrict__ b3,
    const float* __restrict__ X, float* __restrict__ xrec,
    float* __restrict__ lhp)
{
    __shared__ float y1[784];    // 16x7x7
    __shared__ float y2[1568];   // 8x14x14
    __shared__ float w2s[3200];  // dec_w2 [8][16][5][5]
    __shared__ float w3s[200];   // dec_w3 [1][8][5][5]
    __shared__ float zs[8];
    __shared__ float red[256];
    int b = blockIdx.x, tid = threadIdx.x;

    if (tid < 8) zs[tid] = zt[b * 8 + tid];
    for (int i = tid; i < 3200; i += 256) w2s[i] = w2[i];
    if (tid < 200) w3s[tid] = w3[tid];
    __syncthreads();

    // y1 = relu(M1 @ z + bias)   (fc3 + convT1 fused)
    for (int m = tid; m < 784; m += 256) {
        const float* rw = M1 + m * 9;
        float acc = rw[8];
        #pragma unroll
        for (int j = 0; j < 8; ++j) acc += rw[j] * zs[j];
        y1[m] = fmaxf(acc, 0.f);
    }
    __syncthreads();

    // convT2: 16->8, 7->14 (out_pad=1)
    for (int idx = tid; idx < 1568; idx += 256) {
        int oc = idx / 196, r = idx % 196, oy = r / 14, ox = r % 14;
        float acc = b2[oc];
        for (int ky = 0; ky < 5; ++ky) {
            int ty = oy + ky - 2;
            if (ty < 0 || (ty & 1)) continue;
            int iy = ty >> 1; if (iy >= 7) continue;
            for (int kx = 0; kx < 5; ++kx) {
                int tx = ox + kx - 2;
                if (tx < 0 || (tx & 1)) continue;
                int ix = tx >> 1; if (ix >= 7) continue;
                for (int ic = 0; ic < 16; ++ic)
                    acc += w2s[((oc * 16 + ic) * 5 + ky) * 5 + kx] * y1[ic * 49 + iy * 7 + ix];
            }
        }
        y2[idx] = fmaxf(acc, 0.f);
    }
    __syncthreads();

    // convT3: 8->1, 14->28 (out_pad=1), sigmoid, Xrec write + lhood partial
    float part = 0.f;
    for (int idx = tid; idx < 784; idx += 256) {
        int oy = idx / 28, ox = idx % 28;
        float acc = b3[0];
        for (int ky = 0; ky < 5; ++ky) {
            int ty = oy + ky - 2;
            if (ty < 0 || (ty & 1)) continue;
            int iy = ty >> 1; if (iy >= 14) continue;
            for (int kx = 0; kx < 5; ++kx) {
                int tx = ox + kx - 2;
                if (tx < 0 || (tx & 1)) continue;
                int ix = tx >> 1; if (ix >= 14) continue;
                for (int ic = 0; ic < 8; ++ic)
                    acc += w3s[ic * 25 + ky * 5 + kx] * y2[ic * 196 + iy * 14 + ix];
            }
        }
        float p = 1.f / (1.f + expf(-acc));
        size_t o = (size_t)b * 784 + idx;
        xrec[o] = p;
        float x = X[o];   // X flat [N*T*784] matches b*784+idx
        part += logf(EPSL + p) * x + logf(EPSL + 1.f - p) * (1.f - x);
    }
    red[tid] = part;
    __syncthreads();
    for (int s = 128; s > 0; s >>= 1) {
        if (tid < s) red[tid] += red[tid + s];
        __syncthreads();
    }
    if (tid == 0) lhp[b] = red[0];
}

// =====================================================================
// Finalize: reduce lhood/kl partials in double, write scalars.
// =====================================================================
__global__ __launch_bounds__(256) void fin_kernel(
    const float* __restrict__ lhp, const float* __restrict__ klp,
    float* __restrict__ out)
{
    __shared__ double red[256];
    int tid = threadIdx.x;
    double s = 0.0;
    for (int i = tid; i < 12800; i += 256) s += (double)lhp[i];
    red[tid] = s;
    __syncthreads();
    for (int st = 128; st > 0; st >>= 1) {
        if (tid < st) red[tid] += red[tid + st];
        __syncthreads();
    }
    double lh = red[0];
    __syncthreads();
    red[tid] = (double)klp[tid];
    __syncthreads();
    for (int st = 128; st > 0; st >>= 1) {
        if (tid < st) red[tid] += red[tid + st];
        __syncthreads();
    }
    if (tid == 0) {
        out[LH_OFF] = (float)(lh / 256.0);
        out[KL_OFF] = (float)(red[0] / 2048.0);
    }
}

extern "C" void kernel_launch(void* const* d_in, const int* in_sizes, int n_in,
                              void* d_out, int out_size, void* d_ws, size_t ws_size,
                              hipStream_t stream) {
    const float* X     = (const float*)d_in[0];
    const float* eps   = (const float*)d_in[1];
    const float* ew1   = (const float*)d_in[2];
    const float* eb1   = (const float*)d_in[3];
    const float* ew2   = (const float*)d_in[4];
    const float* eb2   = (const float*)d_in[5];
    const float* ew3   = (const float*)d_in[6];
    const float* eb3   = (const float*)d_in[7];
    const float* fc1w  = (const float*)d_in[8];
    const float* fc1b  = (const float*)d_in[9];
    const float* fc2w  = (const float*)d_in[10];
    const float* fc2b  = (const float*)d_in[11];
    const float* fw1   = (const float*)d_in[12];
    const float* fb1   = (const float*)d_in[13];
    const float* fw2   = (const float*)d_in[14];
    const float* fb2   = (const float*)d_in[15];
    const float* fw3   = (const float*)d_in[16];
    const float* fb3   = (const float*)d_in[17];
    const float* fc3w  = (const float*)d_in[18];
    const float* fc3b  = (const float*)d_in[19];
    const float* dw1   = (const float*)d_in[20];
    const float* db1   = (const float*)d_in[21];
    const float* dw2   = (const float*)d_in[22];
    const float* db2   = (const float*)d_in[23];
    const float* dw3   = (const float*)d_in[24];
    const float* db3   = (const float*)d_in[25];

    float* out = (float*)d_out;
    char* ws = (char*)d_ws;
    float* lhp = (float*)ws;                  // 12800 floats
    float* klp = (float*)(ws + 51200);        // 256 floats
    float* z0  = (float*)(ws + 52224);        // 2048 floats
    float* M1  = (float*)(ws + 60416);        // 7056 floats

    prep_kernel<<<28, 256, 0, stream>>>(fc3w, fc3b, dw1, db1, M1);
    enc_kernel<<<256, 256, 0, stream>>>(X, eps, ew1, eb1, ew2, eb2, ew3, eb3,
                                        fc1w, fc1b, fc2w, fc2b, out, z0, klp);
    ode_kernel<<<256, 128, 0, stream>>>(z0, fw1, fb1, fw2, fb2, fw3, fb3, out + ZT_OFF);
    dec_kernel<<<12800, 256, 0, stream>>>(M1, out + ZT_OFF, dw2, db2, dw3, db3,
                                          X, out + XREC_OFF, lhp);
    fin_kernel<<<1, 256, 0, stream>>>(lhp, klp, out);
}

// Round 2
// 821.750 us; speedup vs baseline: 2.5247x; 2.5247x over previous
//
#include <hip/hip_runtime.h>
#include <math.h>

#define DT 0.1f
#define EPSL 1e-5f

// ---- output layout (float32, concatenated in reference return order) ----
#define XREC_OFF 0
#define QM_OFF   10035200
#define QV_OFF   10037248
#define ZT_OFF   10039296
#define LH_OFF   10141696
#define KL_OFF   10141697

// ---- workspace layout (bytes) ----
// lhp  float[3200]   @ 0       (per-dec-block lhood partials)
// klp  float[256]    @ 12800
// z0   float[2048]   @ 13824
// M1p  float[784*12] @ 22016   (fc3+convT1 fused; row m: 8 w, bias, 3 pad; 16B-aligned rows)
// Wc2  float[3200]   @ 59648   (dec_w2 repacked per parity class: [cls][ic][oc][taps])
// Wc3  float[200]    @ 72448   (dec_w3 repacked per parity class: [cls][ic][taps])

// =====================================================================
// Prep: build M1p + parity-class repacked decoder weights.
// Parity decomposition of convT(k=5,s=2,p=2): output (oy,ox) with
// cy=oy&1,cx=ox&1 uses ky=2*dy+cy (dy<ny, ny=cy?2:3), iy=oy/2-1+dy+cy*?
//   cy=0: iy = oy/2 - 1 + dy ; cy=1: iy = oy/2 + dy   (padded idx = iy+1)
// =====================================================================
__global__ __launch_bounds__(256) void prep_kernel(
    const float* __restrict__ fc3w, const float* __restrict__ fc3b,
    const float* __restrict__ dw1, const float* __restrict__ db1,
    const float* __restrict__ dw2, const float* __restrict__ dw3,
    float* __restrict__ M1p, float* __restrict__ Wc2, float* __restrict__ Wc3)
{
    int idx = blockIdx.x * 256 + threadIdx.x;
    if (idx < 9408) {                       // M1p [784][12]
        int m = idx / 12, j = idx % 12;
        float acc = 0.f;
        if (j < 9) {
            int oc = m / 49, r = m % 49, oy = r / 7, ox = r % 7;
            acc = (j == 8) ? db1[oc] : 0.f;
            for (int ky = 0; ky < 5; ++ky) {
                int ty = oy + ky - 2;
                if (ty < 0 || (ty & 1)) continue;
                int iy = ty >> 1; if (iy >= 4) continue;
                for (int kx = 0; kx < 5; ++kx) {
                    int tx = ox + kx - 2;
                    if (tx < 0 || (tx & 1)) continue;
                    int ix = tx >> 1; if (ix >= 4) continue;
                    for (int ic = 0; ic < 32; ++ic) {
                        float wv = dw1[((oc * 32 + ic) * 5 + ky) * 5 + kx];
                        int mi = ic * 16 + iy * 4 + ix;
                        acc += wv * ((j < 8) ? fc3w[mi * 8 + j] : fc3b[mi]);
                    }
                }
            }
        }
        M1p[idx] = acc;
    } else if (idx < 9408 + 3200) {         // Wc2 repack, dw2 [oc=8][ic=16][ky][kx]
        int iw = idx - 9408;
        int kx = iw % 5, t1 = iw / 5, ky = t1 % 5, t2 = t1 / 5, ic = t2 % 16, oc = t2 / 16;
        int cy = ky & 1, cx = kx & 1, dy = ky >> 1, dx = kx >> 1;
        int ny = cy ? 2 : 3, nx = cx ? 2 : 3, nt = ny * nx;
        const int off2[4] = {0, 1152, 1920, 2688};
        Wc2[off2[cy * 2 + cx] + (ic * 8 + oc) * nt + dy * nx + dx] = dw2[iw];
    } else if (idx < 9408 + 3200 + 200) {   // Wc3 repack, dw3 [1][ic=8][ky][kx]
        int iw = idx - 12608;
        int kx = iw % 5, t1 = iw / 5, ky = t1 % 5, ic = t1 / 5;
        int cy = ky & 1, cx = kx & 1, dy = ky >> 1, dx = kx >> 1;
        int ny = cy ? 2 : 3, nx = cx ? 2 : 3, nt = ny * nx;
        const int off3[4] = {0, 72, 120, 168};
        Wc3[off3[cy * 2 + cx] + ic * nt + dy * nx + dx] = dw3[iw];
    }
}

// =====================================================================
// Encoder: one block per sample (unchanged from R0 except ws offsets).
// =====================================================================
__global__ __launch_bounds__(256) void enc_kernel(
    const float* __restrict__ X, const float* __restrict__ eps,
    const float* __restrict__ w1, const float* __restrict__ b1,
    const float* __restrict__ w2, const float* __restrict__ b2,
    const float* __restrict__ w3, const float* __restrict__ b3,
    const float* __restrict__ fc1w, const float* __restrict__ fc1b,
    const float* __restrict__ fc2w, const float* __restrict__ fc2b,
    float* __restrict__ out, float* __restrict__ z0, float* __restrict__ klp)
{
    __shared__ float img[784];
    __shared__ float a1[8 * 196];
    __shared__ float a2[16 * 49];
    __shared__ float h[512];
    __shared__ float kl_s[8];
    int n = blockIdx.x, tid = threadIdx.x;

    const float* xi = X + (size_t)n * 39200;
    for (int i = tid; i < 784; i += 256) img[i] = xi[i];
    __syncthreads();

    for (int idx = tid; idx < 1568; idx += 256) {
        int oc = idx / 196, r = idx % 196, oy = r / 14, ox = r % 14;
        float acc = b1[oc];
        for (int ky = 0; ky < 5; ++ky) {
            int iy = 2 * oy - 2 + ky; if (iy < 0 || iy >= 28) continue;
            for (int kx = 0; kx < 5; ++kx) {
                int ix = 2 * ox - 2 + kx; if (ix < 0 || ix >= 28) continue;
                acc += w1[oc * 25 + ky * 5 + kx] * img[iy * 28 + ix];
            }
        }
        a1[idx] = fmaxf(acc, 0.f);
    }
    __syncthreads();

    for (int idx = tid; idx < 784; idx += 256) {
        int oc = idx / 49, r = idx % 49, oy = r / 7, ox = r % 7;
        float acc = b2[oc];
        for (int ic = 0; ic < 8; ++ic)
            for (int ky = 0; ky < 5; ++ky) {
                int iy = 2 * oy - 2 + ky; if (iy < 0 || iy >= 14) continue;
                for (int kx = 0; kx < 5; ++kx) {
                    int ix = 2 * ox - 2 + kx; if (ix < 0 || ix >= 14) continue;
                    acc += w2[((oc * 8 + ic) * 5 + ky) * 5 + kx] * a1[ic * 196 + iy * 14 + ix];
                }
            }
        a2[idx] = fmaxf(acc, 0.f);
    }
    __syncthreads();

    for (int idx = tid; idx < 512; idx += 256) {
        int oc = idx / 16, r = idx % 16, oy = r / 4, ox = r % 4;
        float acc = b3[oc];
        for (int ic = 0; ic < 16; ++ic)
            for (int ky = 0; ky < 5; ++ky) {
                int iy = 2 * oy - 2 + ky; if (iy < 0 || iy >= 7) continue;
                for (int kx = 0; kx < 5; ++kx) {
                    int ix = 2 * ox - 2 + kx; if (ix < 0 || ix >= 7) continue;
                    acc += w3[((oc * 16 + ic) * 5 + ky) * 5 + kx] * a2[ic * 49 + iy * 7 + ix];
                }
            }
        h[idx] = fmaxf(acc, 0.f);
    }
    __syncthreads();

    if (tid < 8) {
        float m = fc1b[tid], lv = fc2b[tid];
        for (int k = 0; k < 512; ++k) {
            float hv = h[k];
            m  += fc1w[tid * 512 + k] * hv;
            lv += fc2w[tid * 512 + k] * hv;
        }
        float v = fmaxf(lv, 0.f) + log1pf(expf(-fabsf(lv)));
        float z = m + eps[n * 8 + tid] * v;
        out[QM_OFF + n * 8 + tid] = m;
        out[QV_OFF + n * 8 + tid] = v;
        z0[n * 8 + tid] = z;
        kl_s[tid] = -logf(v) + 0.5f * (v * v + m * m) - 0.5f;
    }
    __syncthreads();
    if (tid == 0) {
        float s = 0.f;
        for (int i = 0; i < 8; ++i) s += kl_s[i];
        klp[n] = s;
    }
}

// =====================================================================
// ODE: one block per sample. v2: 4-way split accumulators in layers 2/3
// to break the dependent-FMA chain (100*4cyc -> ~25*4cyc).
// =====================================================================
__global__ __launch_bounds__(128) void ode_kernel(
    const float* __restrict__ z0,
    const float* __restrict__ fw1, const float* __restrict__ fb1,
    const float* __restrict__ fw2, const float* __restrict__ fb2,
    const float* __restrict__ fw3, const float* __restrict__ fb3,
    float* __restrict__ ztg)
{
    __shared__ float w1t[800];
    __shared__ float b1s[100];
    __shared__ float w2t[10000];  // [k][j]
    __shared__ float b2s[100];
    __shared__ float w3s[800];    // [i][k]
    __shared__ float b3s[8];
    __shared__ float v[8], zc[8], kk[3][8], a1[100], h2[100];
    int n = blockIdx.x, tid = threadIdx.x;

    for (int i = tid; i < 800; i += 128) { int j = i >> 3, k = i & 7; w1t[k * 100 + j] = fw1[i]; }
    for (int i = tid; i < 10000; i += 128) { int j = i / 100, k = i % 100; w2t[k * 100 + j] = fw2[i]; }
    for (int i = tid; i < 800; i += 128) w3s[i] = fw3[i];
    for (int i = tid; i < 100; i += 128) { b1s[i] = fb1[i]; b2s[i] = fb2[i]; }
    if (tid < 8) {
        b3s[tid] = fb3[tid];
        float z = z0[n * 8 + tid];
        zc[tid] = z; v[tid] = z;
        ztg[n * 400 + tid] = z;
    }
    __syncthreads();

    for (int t = 1; t < 50; ++t) {
        #pragma unroll 1
        for (int st = 0; st < 4; ++st) {
            if (tid < 100) {
                float acc = b1s[tid];
                #pragma unroll
                for (int k = 0; k < 8; ++k) acc += w1t[k * 100 + tid] * v[k];
                a1[tid] = fmaxf(acc, 0.f);
            }
            __syncthreads();
            if (tid < 100) {
                float s0 = 0.f, s1 = 0.f, s2 = 0.f, s3 = 0.f;
                #pragma unroll
                for (int k = 0; k < 100; k += 4) {
                    s0 += w2t[(k + 0) * 100 + tid] * a1[k + 0];
                    s1 += w2t[(k + 1) * 100 + tid] * a1[k + 1];
                    s2 += w2t[(k + 2) * 100 + tid] * a1[k + 2];
                    s3 += w2t[(k + 3) * 100 + tid] * a1[k + 3];
                }
                h2[tid] = fmaxf(b2s[tid] + ((s0 + s1) + (s2 + s3)), 0.f);
            }
            __syncthreads();
            if (tid < 8) {
                float s0 = 0.f, s1 = 0.f, s2 = 0.f, s3 = 0.f;
                const float* wr = w3s + tid * 100;
                #pragma unroll
                for (int k = 0; k < 100; k += 4) {
                    s0 += wr[k + 0] * h2[k + 0];
                    s1 += wr[k + 1] * h2[k + 1];
                    s2 += wr[k + 2] * h2[k + 2];
                    s3 += wr[k + 3] * h2[k + 3];
                }
                float acc = b3s[tid] + ((s0 + s1) + (s2 + s3));
                if (st < 3) {
                    kk[st][tid] = acc;
                    float c = (st == 2) ? DT : 0.5f * DT;
                    v[tid] = zc[tid] + c * acc;
                } else {
                    float zn = zc[tid] + (DT / 6.f) *
                        (kk[0][tid] + 2.f * kk[1][tid] + 2.f * kk[2][tid] + acc);
                    zc[tid] = zn; v[tid] = zn;
                    ztg[n * 400 + t * 8 + tid] = zn;
                }
            }
            __syncthreads();
        }
    }
}

// =====================================================================
// Decoder v2: 4 samples/block, parity-class branchless convs,
// weights via uniform (scalar) loads, halo-padded LDS activations.
// =====================================================================
template<int CY, int CX>
__device__ __forceinline__ void convt2_cls(
    int s, int i, int j,
    const float (*y1p)[16][9][9],
    const float* __restrict__ Wc2, const float* __restrict__ db2,
    float (*y2p)[8][16][16])
{
    constexpr int NY = CY ? 2 : 3, NX = CX ? 2 : 3, NT = NY * NX;
    constexpr int OFF = (CY == 0) ? (CX == 0 ? 0 : 1152) : (CX == 0 ? 1920 : 2688);
    float acc[8];
    #pragma unroll
    for (int oc = 0; oc < 8; ++oc) acc[oc] = db2[oc];
    const float* wc = Wc2 + OFF;
    #pragma unroll 1
    for (int ic = 0; ic < 16; ++ic) {
        float yv[NT];
        #pragma unroll
        for (int dy = 0; dy < NY; ++dy)
            #pragma unroll
            for (int dx = 0; dx < NX; ++dx)
                yv[dy * NX + dx] = y1p[s][ic][i + dy + CY][j + dx + CX];
        const float* w = wc + ic * 8 * NT;     // uniform address -> s_load
        #pragma unroll
        for (int oc = 0; oc < 8; ++oc)
            #pragma unroll
            for (int t = 0; t < NT; ++t)
                acc[oc] += w[oc * NT + t] * yv[t];
    }
    #pragma unroll
    for (int oc = 0; oc < 8; ++oc)
        y2p[s][oc][1 + 2 * i + CY][1 + 2 * j + CX] = fmaxf(acc[oc], 0.f);
}

template<int CY, int CX>
__device__ __forceinline__ void convt3_cls(
    int s, int u, int vv,
    const float (*y2p)[8][16][16],
    const float* __restrict__ Wc3, float acc[2][2])
{
    constexpr int NY = CY ? 2 : 3, NX = CX ? 2 : 3, NT = NY * NX;
    constexpr int OFF = (CY == 0) ? (CX == 0 ? 0 : 72) : (CX == 0 ? 120 : 168);
    constexpr int RY = 1 + NY, RX = 1 + NX;    // 2x2 pixel tile + taps
    const float* wc = Wc3 + OFF;
    #pragma unroll 1
    for (int ic = 0; ic < 8; ++ic) {
        float yv[RY][RX];
        #pragma unroll
        for (int ry = 0; ry < RY; ++ry)
            #pragma unroll
            for (int rx = 0; rx < RX; ++rx)
                yv[ry][rx] = y2p[s][ic][2 * u + CY + ry][2 * vv + CX + rx];
        #pragma unroll
        for (int di = 0; di < 2; ++di)
            #pragma unroll
            for (int dj = 0; dj < 2; ++dj)
                #pragma unroll
                for (int dy = 0; dy < NY; ++dy)
                    #pragma unroll
                    for (int dx = 0; dx < NX; ++dx)
                        acc[di][dj] += wc[ic * NT + dy * NX + dx] * yv[di + dy][dj + dx];
    }
}

template<int CY, int CX>
__device__ __forceinline__ float emit_cls(
    int u, int vv, size_t base, const float acc[2][2],
    const float* __restrict__ X, float* __restrict__ xrec)
{
    float part = 0.f;
    #pragma unroll
    for (int di = 0; di < 2; ++di)
        #pragma unroll
        for (int dj = 0; dj < 2; ++dj) {
            int oy = 4 * u + 2 * di + CY, ox = 4 * vv + 2 * dj + CX;
            float p = 1.f / (1.f + expf(-acc[di][dj]));
            size_t o = base + oy * 28 + ox;
            xrec[o] = p;
            float x = X[o];
            part += logf(EPSL + p) * x + logf(EPSL + 1.f - p) * (1.f - x);
        }
    return part;
}

__global__ __launch_bounds__(256) void dec_kernel(
    const float* __restrict__ M1p, const float* __restrict__ zt,
    const float* __restrict__ Wc2, const float* __restrict__ db2,
    const float* __restrict__ Wc3, const float* __restrict__ db3,
    const float* __restrict__ X, float* __restrict__ xrec,
    float* __restrict__ lhp)
{
    __shared__ float y1p[4][16][9][9];    // halo-padded 7x7 -> 9x9
    __shared__ float y2p[4][8][16][16];   // halo-padded 14x14 -> 16x16
    __shared__ float red[256];
    int blk = blockIdx.x, tid = threadIdx.x;

    for (int idx = tid; idx < 5184; idx += 256) ((float*)y1p)[idx] = 0.f;
    for (int idx = tid; idx < 8192; idx += 256) ((float*)y2p)[idx] = 0.f;
    __syncthreads();

    // phase 0: y1 = relu(M1 @ z + b) for 4 samples; z in SGPRs (uniform loads)
    {
        float zr[4][8];
        const float* zp = zt + (size_t)blk * 32;
        #pragma unroll
        for (int s = 0; s < 4; ++s)
            #pragma unroll
            for (int jj = 0; jj < 8; ++jj) zr[s][jj] = zp[s * 8 + jj];
        for (int m = tid; m < 784; m += 256) {
            const float4* row = (const float4*)(M1p + m * 12);
            float4 r0 = row[0], r1 = row[1], r2 = row[2];
            int oc = m / 49, r = m % 49, oy = r / 7, ox = r % 7;
            #pragma unroll
            for (int s = 0; s < 4; ++s) {
                float acc = r2.x;
                acc += r0.x * zr[s][0] + r0.y * zr[s][1] + r0.z * zr[s][2] + r0.w * zr[s][3]
                     + r1.x * zr[s][4] + r1.y * zr[s][5] + r1.z * zr[s][6] + r1.w * zr[s][7];
                y1p[s][oc][1 + oy][1 + ox] = fmaxf(acc, 0.f);
            }
        }
    }
    __syncthreads();

    // phase 1: convT2 (16->8, 7->14), 4 parity classes, no internal syncs
    if (tid < 196) {
        int s = tid / 49, p = tid % 49, i = p / 7, j = p % 7;
        convt2_cls<0, 0>(s, i, j, y1p, Wc2, db2, y2p);
        convt2_cls<0, 1>(s, i, j, y1p, Wc2, db2, y2p);
        convt2_cls<1, 0>(s, i, j, y1p, Wc2, db2, y2p);
        convt2_cls<1, 1>(s, i, j, y1p, Wc2, db2, y2p);
    }
    __syncthreads();

    // phase 2: convT3 (8->1, 14->28) with 2x2 pixel tiles + sigmoid + lhood
    float part = 0.f;
    if (tid < 196) {
        int s = tid / 49, q = tid % 49, u = q / 7, vv = q % 7;
        size_t base = ((size_t)blk * 4 + s) * 784;
        float b3v = db3[0];
        {
            float acc[2][2] = {{b3v, b3v}, {b3v, b3v}};
            convt3_cls<0, 0>(s, u, vv, y2p, Wc3, acc);
            part += emit_cls<0, 0>(u, vv, base, acc, X, xrec);
        }
        {
            float acc[2][2] = {{b3v, b3v}, {b3v, b3v}};
            convt3_cls<0, 1>(s, u, vv, y2p, Wc3, acc);
            part += emit_cls<0, 1>(u, vv, base, acc, X, xrec);
        }
        {
            float acc[2][2] = {{b3v, b3v}, {b3v, b3v}};
            convt3_cls<1, 0>(s, u, vv, y2p, Wc3, acc);
            part += emit_cls<1, 0>(u, vv, base, acc, X, xrec);
        }
        {
            float acc[2][2] = {{b3v, b3v}, {b3v, b3v}};
            convt3_cls<1, 1>(s, u, vv, y2p, Wc3, acc);
            part += emit_cls<1, 1>(u, vv, base, acc, X, xrec);
        }
    }
    red[tid] = part;
    __syncthreads();
    for (int st = 128; st > 0; st >>= 1) {
        if (tid < st) red[tid] += red[tid + st];
        __syncthreads();
    }
    if (tid == 0) lhp[blk] = red[0];
}

// =====================================================================
// Finalize: reduce lhood/kl partials in double, write scalars.
// =====================================================================
__global__ __launch_bounds__(256) void fin_kernel(
    const float* __restrict__ lhp, const float* __restrict__ klp,
    float* __restrict__ out)
{
    __shared__ double red[256];
    int tid = threadIdx.x;
    double s = 0.0;
    for (int i = tid; i < 3200; i += 256) s += (double)lhp[i];
    red[tid] = s;
    __syncthreads();
    for (int st = 128; st > 0; st >>= 1) {
        if (tid < st) red[tid] += red[tid + st];
        __syncthreads();
    }
    double lh = red[0];
    __syncthreads();
    red[tid] = (double)klp[tid];
    __syncthreads();
    for (int st = 128; st > 0; st >>= 1) {
        if (tid < st) red[tid] += red[tid + st];
        __syncthreads();
    }
    if (tid == 0) {
        out[LH_OFF] = (float)(lh / 256.0);
        out[KL_OFF] = (float)(red[0] / 2048.0);
    }
}

extern "C" void kernel_launch(void* const* d_in, const int* in_sizes, int n_in,
                              void* d_out, int out_size, void* d_ws, size_t ws_size,
                              hipStream_t stream) {
    const float* X     = (const float*)d_in[0];
    const float* eps   = (const float*)d_in[1];
    const float* ew1   = (const float*)d_in[2];
    const float* eb1   = (const float*)d_in[3];
    const float* ew2   = (const float*)d_in[4];
    const float* eb2   = (const float*)d_in[5];
    const float* ew3   = (const float*)d_in[6];
    const float* eb3   = (const float*)d_in[7];
    const float* fc1w  = (const float*)d_in[8];
    const float* fc1b  = (const float*)d_in[9];
    const float* fc2w  = (const float*)d_in[10];
    const float* fc2b  = (const float*)d_in[11];
    const float* fw1   = (const float*)d_in[12];
    const float* fb1   = (const float*)d_in[13];
    const float* fw2   = (const float*)d_in[14];
    const float* fb2   = (const float*)d_in[15];
    const float* fw3   = (const float*)d_in[16];
    const float* fb3   = (const float*)d_in[17];
    const float* fc3w  = (const float*)d_in[18];
    const float* fc3b  = (const float*)d_in[19];
    const float* dw1   = (const float*)d_in[20];
    const float* db1   = (const float*)d_in[21];
    const float* dw2   = (const float*)d_in[22];
    const float* db2   = (const float*)d_in[23];
    const float* dw3   = (const float*)d_in[24];
    const float* db3   = (const float*)d_in[25];

    float* out = (float*)d_out;
    char* ws = (char*)d_ws;
    float* lhp = (float*)ws;                  // 3200 floats
    float* klp = (float*)(ws + 12800);        // 256 floats
    float* z0  = (float*)(ws + 13824);        // 2048 floats
    float* M1p = (float*)(ws + 22016);        // 9408 floats (16B aligned)
    float* Wc2 = (float*)(ws + 59648);        // 3200 floats
    float* Wc3 = (float*)(ws + 72448);        // 200 floats

    prep_kernel<<<51, 256, 0, stream>>>(fc3w, fc3b, dw1, db1, dw2, dw3, M1p, Wc2, Wc3);
    enc_kernel<<<256, 256, 0, stream>>>(X, eps, ew1, eb1, ew2, eb2, ew3, eb3,
                                        fc1w, fc1b, fc2w, fc2b, out, z0, klp);
    ode_kernel<<<256, 128, 0, stream>>>(z0, fw1, fb1, fw2, fb2, fw3, fb3, out + ZT_OFF);
    dec_kernel<<<3200, 256, 0, stream>>>(M1p, out + ZT_OFF, Wc2, db2, Wc3, db3,
                                         X, out + XREC_OFF, lhp);
    fin_kernel<<<1, 256, 0, stream>>>(lhp, klp, out);
}

// Round 3
// 713.665 us; speedup vs baseline: 2.9070x; 1.1515x over previous
//
#include <hip/hip_runtime.h>
#include <math.h>

#define DT 0.1f
#define EPSL 1e-5f

// ---- output layout (float32, concatenated in reference return order) ----
#define XREC_OFF 0
#define QM_OFF   10035200
#define QV_OFF   10037248
#define ZT_OFF   10039296
#define LH_OFF   10141696
#define KL_OFF   10141697

// ---- workspace layout (bytes) ----
// lhp  float[3200]   @ 0
// klp  float[256]    @ 12800
// z0   float[2048]   @ 13824
// M1p  float[784*12] @ 22016
// Wc2  float[3200]   @ 59648
// Wc3  float[200]    @ 72448

// =====================================================================
// Prep: build M1p + parity-class repacked decoder weights.
// =====================================================================
__global__ __launch_bounds__(256) void prep_kernel(
    const float* __restrict__ fc3w, const float* __restrict__ fc3b,
    const float* __restrict__ dw1, const float* __restrict__ db1,
    const float* __restrict__ dw2, const float* __restrict__ dw3,
    float* __restrict__ M1p, float* __restrict__ Wc2, float* __restrict__ Wc3)
{
    int idx = blockIdx.x * 256 + threadIdx.x;
    if (idx < 9408) {                       // M1p [784][12]
        int m = idx / 12, j = idx % 12;
        float acc = 0.f;
        if (j < 9) {
            int oc = m / 49, r = m % 49, oy = r / 7, ox = r % 7;
            acc = (j == 8) ? db1[oc] : 0.f;
            for (int ky = 0; ky < 5; ++ky) {
                int ty = oy + ky - 2;
                if (ty < 0 || (ty & 1)) continue;
                int iy = ty >> 1; if (iy >= 4) continue;
                for (int kx = 0; kx < 5; ++kx) {
                    int tx = ox + kx - 2;
                    if (tx < 0 || (tx & 1)) continue;
                    int ix = tx >> 1; if (ix >= 4) continue;
                    for (int ic = 0; ic < 32; ++ic) {
                        float wv = dw1[((oc * 32 + ic) * 5 + ky) * 5 + kx];
                        int mi = ic * 16 + iy * 4 + ix;
                        acc += wv * ((j < 8) ? fc3w[mi * 8 + j] : fc3b[mi]);
                    }
                }
            }
        }
        M1p[idx] = acc;
    } else if (idx < 9408 + 3200) {         // Wc2 repack, dw2 [oc=8][ic=16][ky][kx]
        int iw = idx - 9408;
        int kx = iw % 5, t1 = iw / 5, ky = t1 % 5, t2 = t1 / 5, ic = t2 % 16, oc = t2 / 16;
        int cy = ky & 1, cx = kx & 1, dy = ky >> 1, dx = kx >> 1;
        int ny = cy ? 2 : 3, nx = cx ? 2 : 3, nt = ny * nx;
        const int off2[4] = {0, 1152, 1920, 2688};
        Wc2[off2[cy * 2 + cx] + (ic * 8 + oc) * nt + dy * nx + dx] = dw2[iw];
    } else if (idx < 9408 + 3200 + 200) {   // Wc3 repack
        int iw = idx - 12608;
        int kx = iw % 5, t1 = iw / 5, ky = t1 % 5, ic = t1 / 5;
        int cy = ky & 1, cx = kx & 1, dy = ky >> 1, dx = kx >> 1;
        int ny = cy ? 2 : 3, nx = cx ? 2 : 3, nt = ny * nx;
        const int off3[4] = {0, 72, 120, 168};
        Wc3[off3[cy * 2 + cx] + ic * nt + dy * nx + dx] = dw3[iw];
    }
}

// =====================================================================
// Encoder: one block per sample (unchanged).
// =====================================================================
__global__ __launch_bounds__(256) void enc_kernel(
    const float* __restrict__ X, const float* __restrict__ eps,
    const float* __restrict__ w1, const float* __restrict__ b1,
    const float* __restrict__ w2, const float* __restrict__ b2,
    const float* __restrict__ w3, const float* __restrict__ b3,
    const float* __restrict__ fc1w, const float* __restrict__ fc1b,
    const float* __restrict__ fc2w, const float* __restrict__ fc2b,
    float* __restrict__ out, float* __restrict__ z0, float* __restrict__ klp)
{
    __shared__ float img[784];
    __shared__ float a1[8 * 196];
    __shared__ float a2[16 * 49];
    __shared__ float h[512];
    __shared__ float kl_s[8];
    int n = blockIdx.x, tid = threadIdx.x;

    const float* xi = X + (size_t)n * 39200;
    for (int i = tid; i < 784; i += 256) img[i] = xi[i];
    __syncthreads();

    for (int idx = tid; idx < 1568; idx += 256) {
        int oc = idx / 196, r = idx % 196, oy = r / 14, ox = r % 14;
        float acc = b1[oc];
        for (int ky = 0; ky < 5; ++ky) {
            int iy = 2 * oy - 2 + ky; if (iy < 0 || iy >= 28) continue;
            for (int kx = 0; kx < 5; ++kx) {
                int ix = 2 * ox - 2 + kx; if (ix < 0 || ix >= 28) continue;
                acc += w1[oc * 25 + ky * 5 + kx] * img[iy * 28 + ix];
            }
        }
        a1[idx] = fmaxf(acc, 0.f);
    }
    __syncthreads();

    for (int idx = tid; idx < 784; idx += 256) {
        int oc = idx / 49, r = idx % 49, oy = r / 7, ox = r % 7;
        float acc = b2[oc];
        for (int ic = 0; ic < 8; ++ic)
            for (int ky = 0; ky < 5; ++ky) {
                int iy = 2 * oy - 2 + ky; if (iy < 0 || iy >= 14) continue;
                for (int kx = 0; kx < 5; ++kx) {
                    int ix = 2 * ox - 2 + kx; if (ix < 0 || ix >= 14) continue;
                    acc += w2[((oc * 8 + ic) * 5 + ky) * 5 + kx] * a1[ic * 196 + iy * 14 + ix];
                }
            }
        a2[idx] = fmaxf(acc, 0.f);
    }
    __syncthreads();

    for (int idx = tid; idx < 512; idx += 256) {
        int oc = idx / 16, r = idx % 16, oy = r / 4, ox = r % 4;
        float acc = b3[oc];
        for (int ic = 0; ic < 16; ++ic)
            for (int ky = 0; ky < 5; ++ky) {
                int iy = 2 * oy - 2 + ky; if (iy < 0 || iy >= 7) continue;
                for (int kx = 0; kx < 5; ++kx) {
                    int ix = 2 * ox - 2 + kx; if (ix < 0 || ix >= 7) continue;
                    acc += w3[((oc * 16 + ic) * 5 + ky) * 5 + kx] * a2[ic * 49 + iy * 7 + ix];
                }
            }
        h[idx] = fmaxf(acc, 0.f);
    }
    __syncthreads();

    if (tid < 8) {
        float m = fc1b[tid], lv = fc2b[tid];
        for (int k = 0; k < 512; ++k) {
            float hv = h[k];
            m  += fc1w[tid * 512 + k] * hv;
            lv += fc2w[tid * 512 + k] * hv;
        }
        float v = fmaxf(lv, 0.f) + log1pf(expf(-fabsf(lv)));
        float z = m + eps[n * 8 + tid] * v;
        out[QM_OFF + n * 8 + tid] = m;
        out[QV_OFF + n * 8 + tid] = v;
        z0[n * 8 + tid] = z;
        kl_s[tid] = -logf(v) + 0.5f * (v * v + m * m) - 0.5f;
    }
    __syncthreads();
    if (tid == 0) {
        float s = 0.f;
        for (int i = 0; i < 8; ++i) s += kl_s[i];
        klp[n] = s;
    }
}

// =====================================================================
// ODE v3: one WAVE (64 lanes) per sample. All weights register-resident;
// cross-lane broadcast via v_readlane; no LDS, no barriers.
// Lane L owns outputs jA=L (.x) and jB=L+64 (.y, zero-padded for L>=36).
// RK4 state lives in lanes 0..7 (lane L holds dim L&7); uniform v is a
// replicated 8-reg array rebuilt by readlane each stage.
// =====================================================================
__device__ __forceinline__ float rl(float v, int lane) {
    return __uint_as_float(__builtin_amdgcn_readlane(__float_as_uint(v), lane));
}
__device__ __forceinline__ float bcast(float lo, float hi, int k) {
    return (k < 64) ? rl(lo, k) : rl(hi, k - 64);
}

__global__ __launch_bounds__(64, 1) void ode_kernel(
    const float* __restrict__ z0,
    const float* __restrict__ fw1, const float* __restrict__ fb1,
    const float* __restrict__ fw2, const float* __restrict__ fb2,
    const float* __restrict__ fw3, const float* __restrict__ fb3,
    float* __restrict__ ztg)
{
    int n = blockIdx.x, L = threadIdx.x;
    bool hiv = (L < 36);
    int jA = L, jB = L + 64, i3 = L & 7;

    // ---- load weights into registers (one-time; L2-resident after first blocks)
    float w1x[8], w1y[8];
    float w2x[100], w2y[100], w3r[100];
    float b1A = fb1[jA], b1B = hiv ? fb1[jB] : 0.f;
    float b2A = fb2[jA], b2B = hiv ? fb2[jB] : 0.f;
    float b3r = fb3[i3];
    #pragma unroll
    for (int k = 0; k < 8; ++k) {
        w1x[k] = fw1[jA * 8 + k];
        w1y[k] = hiv ? fw1[jB * 8 + k] : 0.f;
    }
    #pragma unroll
    for (int k = 0; k < 100; ++k) {
        w2x[k] = fw2[jA * 100 + k];
        w2y[k] = hiv ? fw2[jB * 100 + k] : 0.f;
        w3r[k] = fw3[i3 * 100 + k];
    }

    float zc = z0[n * 8 + i3];          // lane (L&7) holds z_{L&7}
    if (L < 8) ztg[n * 400 + L] = zc;   // zt[n,0,:]
    float vu[8];
    #pragma unroll
    for (int i = 0; i < 8; ++i) vu[i] = rl(zc, i);

    #pragma unroll 1
    for (int t = 1; t < 50; ++t) {
        float zsum = 0.f;
        #pragma unroll 1
        for (int st = 0; st < 4; ++st) {
            // ---- layer 1: 8 -> 100 (per-lane pair) ----
            float aA = b1A, aB = b1B;
            #pragma unroll
            for (int k = 0; k < 8; ++k) {
                aA = fmaf(w1x[k], vu[k], aA);
                aB = fmaf(w1y[k], vu[k], aB);
            }
            aA = fmaxf(aA, 0.f); aB = fmaxf(aB, 0.f);

            // ---- layer 2: 100 -> 100, readlane broadcast, 4-way split accs ----
            float hA0 = b2A, hA1 = 0.f, hA2 = 0.f, hA3 = 0.f;
            float hB0 = b2B, hB1 = 0.f, hB2 = 0.f, hB3 = 0.f;
            #pragma unroll
            for (int k = 0; k < 100; k += 4) {
                float s0 = bcast(aA, aB, k + 0);
                float s1 = bcast(aA, aB, k + 1);
                float s2 = bcast(aA, aB, k + 2);
                float s3 = bcast(aA, aB, k + 3);
                hA0 = fmaf(w2x[k + 0], s0, hA0); hB0 = fmaf(w2y[k + 0], s0, hB0);
                hA1 = fmaf(w2x[k + 1], s1, hA1); hB1 = fmaf(w2y[k + 1], s1, hB1);
                hA2 = fmaf(w2x[k + 2], s2, hA2); hB2 = fmaf(w2y[k + 2], s2, hB2);
                hA3 = fmaf(w2x[k + 3], s3, hA3); hB3 = fmaf(w2y[k + 3], s3, hB3);
            }
            float hA = fmaxf((hA0 + hA1) + (hA2 + hA3), 0.f);
            float hB = fmaxf((hB0 + hB1) + (hB2 + hB3), 0.f);

            // ---- layer 3: 100 -> 8 (lane L&7 owns out dim), 4-way split ----
            float o0 = b3r, o1 = 0.f, o2 = 0.f, o3 = 0.f;
            #pragma unroll
            for (int k = 0; k < 100; k += 4) {
                o0 = fmaf(w3r[k + 0], bcast(hA, hB, k + 0), o0);
                o1 = fmaf(w3r[k + 1], bcast(hA, hB, k + 1), o1);
                o2 = fmaf(w3r[k + 2], bcast(hA, hB, k + 2), o2);
                o3 = fmaf(w3r[k + 3], bcast(hA, hB, k + 3), o3);
            }
            float o = (o0 + o1) + (o2 + o3);

            // ---- RK4 bookkeeping (per-lane; meaningful in lanes 0..7) ----
            float cw = (st == 0 || st == 3) ? (DT / 6.f) : (DT / 3.f);
            zsum = fmaf(cw, o, zsum);
            float vn;
            if (st < 3) {
                float cin = (st == 2) ? DT : 0.5f * DT;
                vn = fmaf(cin, o, zc);
            } else {
                zc = zc + zsum;
                vn = zc;
                if (L < 8) ztg[n * 400 + t * 8 + L] = zc;
            }
            #pragma unroll
            for (int i = 0; i < 8; ++i) vu[i] = rl(vn, i);
        }
    }
}

// =====================================================================
// Decoder v2 (unchanged): 4 samples/block, parity-class branchless convs.
// =====================================================================
template<int CY, int CX>
__device__ __forceinline__ void convt2_cls(
    int s, int i, int j,
    const float (*y1p)[16][9][9],
    const float* __restrict__ Wc2, const float* __restrict__ db2,
    float (*y2p)[8][16][16])
{
    constexpr int NY = CY ? 2 : 3, NX = CX ? 2 : 3, NT = NY * NX;
    constexpr int OFF = (CY == 0) ? (CX == 0 ? 0 : 1152) : (CX == 0 ? 1920 : 2688);
    float acc[8];
    #pragma unroll
    for (int oc = 0; oc < 8; ++oc) acc[oc] = db2[oc];
    const float* wc = Wc2 + OFF;
    #pragma unroll 1
    for (int ic = 0; ic < 16; ++ic) {
        float yv[NT];
        #pragma unroll
        for (int dy = 0; dy < NY; ++dy)
            #pragma unroll
            for (int dx = 0; dx < NX; ++dx)
                yv[dy * NX + dx] = y1p[s][ic][i + dy + CY][j + dx + CX];
        const float* w = wc + ic * 8 * NT;
        #pragma unroll
        for (int oc = 0; oc < 8; ++oc)
            #pragma unroll
            for (int t = 0; t < NT; ++t)
                acc[oc] += w[oc * NT + t] * yv[t];
    }
    #pragma unroll
    for (int oc = 0; oc < 8; ++oc)
        y2p[s][oc][1 + 2 * i + CY][1 + 2 * j + CX] = fmaxf(acc[oc], 0.f);
}

template<int CY, int CX>
__device__ __forceinline__ void convt3_cls(
    int s, int u, int vv,
    const float (*y2p)[8][16][16],
    const float* __restrict__ Wc3, float acc[2][2])
{
    constexpr int NY = CY ? 2 : 3, NX = CX ? 2 : 3, NT = NY * NX;
    constexpr int OFF = (CY == 0) ? (CX == 0 ? 0 : 72) : (CX == 0 ? 120 : 168);
    constexpr int RY = 1 + NY, RX = 1 + NX;
    const float* wc = Wc3 + OFF;
    #pragma unroll 1
    for (int ic = 0; ic < 8; ++ic) {
        float yv[RY][RX];
        #pragma unroll
        for (int ry = 0; ry < RY; ++ry)
            #pragma unroll
            for (int rx = 0; rx < RX; ++rx)
                yv[ry][rx] = y2p[s][ic][2 * u + CY + ry][2 * vv + CX + rx];
        #pragma unroll
        for (int di = 0; di < 2; ++di)
            #pragma unroll
            for (int dj = 0; dj < 2; ++dj)
                #pragma unroll
                for (int dy = 0; dy < NY; ++dy)
                    #pragma unroll
                    for (int dx = 0; dx < NX; ++dx)
                        acc[di][dj] += wc[ic * NT + dy * NX + dx] * yv[di + dy][dj + dx];
    }
}

template<int CY, int CX>
__device__ __forceinline__ float emit_cls(
    int u, int vv, size_t base, const float acc[2][2],
    const float* __restrict__ X, float* __restrict__ xrec)
{
    float part = 0.f;
    #pragma unroll
    for (int di = 0; di < 2; ++di)
        #pragma unroll
        for (int dj = 0; dj < 2; ++dj) {
            int oy = 4 * u + 2 * di + CY, ox = 4 * vv + 2 * dj + CX;
            float p = 1.f / (1.f + expf(-acc[di][dj]));
            size_t o = base + oy * 28 + ox;
            xrec[o] = p;
            float x = X[o];
            part += logf(EPSL + p) * x + logf(EPSL + 1.f - p) * (1.f - x);
        }
    return part;
}

__global__ __launch_bounds__(256) void dec_kernel(
    const float* __restrict__ M1p, const float* __restrict__ zt,
    const float* __restrict__ Wc2, const float* __restrict__ db2,
    const float* __restrict__ Wc3, const float* __restrict__ db3,
    const float* __restrict__ X, float* __restrict__ xrec,
    float* __restrict__ lhp)
{
    __shared__ float y1p[4][16][9][9];
    __shared__ float y2p[4][8][16][16];
    __shared__ float red[256];
    int blk = blockIdx.x, tid = threadIdx.x;

    for (int idx = tid; idx < 5184; idx += 256) ((float*)y1p)[idx] = 0.f;
    for (int idx = tid; idx < 8192; idx += 256) ((float*)y2p)[idx] = 0.f;
    __syncthreads();

    {
        float zr[4][8];
        const float* zp = zt + (size_t)blk * 32;
        #pragma unroll
        for (int s = 0; s < 4; ++s)
            #pragma unroll
            for (int jj = 0; jj < 8; ++jj) zr[s][jj] = zp[s * 8 + jj];
        for (int m = tid; m < 784; m += 256) {
            const float4* row = (const float4*)(M1p + m * 12);
            float4 r0 = row[0], r1 = row[1], r2 = row[2];
            int oc = m / 49, r = m % 49, oy = r / 7, ox = r % 7;
            #pragma unroll
            for (int s = 0; s < 4; ++s) {
                float acc = r2.x;
                acc += r0.x * zr[s][0] + r0.y * zr[s][1] + r0.z * zr[s][2] + r0.w * zr[s][3]
                     + r1.x * zr[s][4] + r1.y * zr[s][5] + r1.z * zr[s][6] + r1.w * zr[s][7];
                y1p[s][oc][1 + oy][1 + ox] = fmaxf(acc, 0.f);
            }
        }
    }
    __syncthreads();

    if (tid < 196) {
        int s = tid / 49, p = tid % 49, i = p / 7, j = p % 7;
        convt2_cls<0, 0>(s, i, j, y1p, Wc2, db2, y2p);
        convt2_cls<0, 1>(s, i, j, y1p, Wc2, db2, y2p);
        convt2_cls<1, 0>(s, i, j, y1p, Wc2, db2, y2p);
        convt2_cls<1, 1>(s, i, j, y1p, Wc2, db2, y2p);
    }
    __syncthreads();

    float part = 0.f;
    if (tid < 196) {
        int s = tid / 49, q = tid % 49, u = q / 7, vv = q % 7;
        size_t base = ((size_t)blk * 4 + s) * 784;
        float b3v = db3[0];
        {
            float acc[2][2] = {{b3v, b3v}, {b3v, b3v}};
            convt3_cls<0, 0>(s, u, vv, y2p, Wc3, acc);
            part += emit_cls<0, 0>(u, vv, base, acc, X, xrec);
        }
        {
            float acc[2][2] = {{b3v, b3v}, {b3v, b3v}};
            convt3_cls<0, 1>(s, u, vv, y2p, Wc3, acc);
            part += emit_cls<0, 1>(u, vv, base, acc, X, xrec);
        }
        {
            float acc[2][2] = {{b3v, b3v}, {b3v, b3v}};
            convt3_cls<1, 0>(s, u, vv, y2p, Wc3, acc);
            part += emit_cls<1, 0>(u, vv, base, acc, X, xrec);
        }
        {
            float acc[2][2] = {{b3v, b3v}, {b3v, b3v}};
            convt3_cls<1, 1>(s, u, vv, y2p, Wc3, acc);
            part += emit_cls<1, 1>(u, vv, base, acc, X, xrec);
        }
    }
    red[tid] = part;
    __syncthreads();
    for (int st = 128; st > 0; st >>= 1) {
        if (tid < st) red[tid] += red[tid + st];
        __syncthreads();
    }
    if (tid == 0) lhp[blk] = red[0];
}

// =====================================================================
// Finalize
// =====================================================================
__global__ __launch_bounds__(256) void fin_kernel(
    const float* __restrict__ lhp, const float* __restrict__ klp,
    float* __restrict__ out)
{
    __shared__ double red[256];
    int tid = threadIdx.x;
    double s = 0.0;
    for (int i = tid; i < 3200; i += 256) s += (double)lhp[i];
    red[tid] = s;
    __syncthreads();
    for (int st = 128; st > 0; st >>= 1) {
        if (tid < st) red[tid] += red[tid + st];
        __syncthreads();
    }
    double lh = red[0];
    __syncthreads();
    red[tid] = (double)klp[tid];
    __syncthreads();
    for (int st = 128; st > 0; st >>= 1) {
        if (tid < st) red[tid] += red[tid + st];
        __syncthreads();
    }
    if (tid == 0) {
        out[LH_OFF] = (float)(lh / 256.0);
        out[KL_OFF] = (float)(red[0] / 2048.0);
    }
}

extern "C" void kernel_launch(void* const* d_in, const int* in_sizes, int n_in,
                              void* d_out, int out_size, void* d_ws, size_t ws_size,
                              hipStream_t stream) {
    const float* X     = (const float*)d_in[0];
    const float* eps   = (const float*)d_in[1];
    const float* ew1   = (const float*)d_in[2];
    const float* eb1   = (const float*)d_in[3];
    const float* ew2   = (const float*)d_in[4];
    const float* eb2   = (const float*)d_in[5];
    const float* ew3   = (const float*)d_in[6];
    const float* eb3   = (const float*)d_in[7];
    const float* fc1w  = (const float*)d_in[8];
    const float* fc1b  = (const float*)d_in[9];
    const float* fc2w  = (const float*)d_in[10];
    const float* fc2b  = (const float*)d_in[11];
    const float* fw1   = (const float*)d_in[12];
    const float* fb1   = (const float*)d_in[13];
    const float* fw2   = (const float*)d_in[14];
    const float* fb2   = (const float*)d_in[15];
    const float* fw3   = (const float*)d_in[16];
    const float* fb3   = (const float*)d_in[17];
    const float* fc3w  = (const float*)d_in[18];
    const float* fc3b  = (const float*)d_in[19];
    const float* dw1   = (const float*)d_in[20];
    const float* db1   = (const float*)d_in[21];
    const float* dw2   = (const float*)d_in[22];
    const float* db2   = (const float*)d_in[23];
    const float* dw3   = (const float*)d_in[24];
    const float* db3   = (const float*)d_in[25];

    float* out = (float*)d_out;
    char* ws = (char*)d_ws;
    float* lhp = (float*)ws;
    float* klp = (float*)(ws + 12800);
    float* z0  = (float*)(ws + 13824);
    float* M1p = (float*)(ws + 22016);
    float* Wc2 = (float*)(ws + 59648);
    float* Wc3 = (float*)(ws + 72448);

    prep_kernel<<<51, 256, 0, stream>>>(fc3w, fc3b, dw1, db1, dw2, dw3, M1p, Wc2, Wc3);
    enc_kernel<<<256, 256, 0, stream>>>(X, eps, ew1, eb1, ew2, eb2, ew3, eb3,
                                        fc1w, fc1b, fc2w, fc2b, out, z0, klp);
    ode_kernel<<<256, 64, 0, stream>>>(z0, fw1, fb1, fw2, fb2, fw3, fb3, out + ZT_OFF);
    dec_kernel<<<3200, 256, 0, stream>>>(M1p, out + ZT_OFF, Wc2, db2, Wc3, db3,
                                         X, out + XREC_OFF, lhp);
    fin_kernel<<<1, 256, 0, stream>>>(lhp, klp, out);
}